// Round 10
// baseline (238.903 us; speedup 1.0000x reference)
//
#include <hip/hip_runtime.h>
#include <hip/hip_bf16.h>

// ---------------------------------------------------------------------------
// B=2, S=2048, D=768, H=12, Dh=64. M = B*S = 4096.
// R24: R23 + attn occupancy fix. V stage buffer single-buffered (K stays
// double): LDS 65536 -> 50688 -> 3 blocks/CU (grid 768 fully co-resident,
// no ragged tail round; 24 waves/CU). Race fenced by 2 barriers/tile:
//   1 issue K[t+1] -> Kbuf^1 | 2 QK^T+softmax | 3 barrier A (V[t]+K[t+1]
//   drained) | 4 PV | 5 barrier B (V reads done) | 6 issue V[t+1] -> Vts.
// Arithmetic order untouched (absmax bit-identical to R23's 0.082).
// Non-attn = R23 verbatim (exp2-domain fold + prep fusion + 2-phase GEMMs).
// ---------------------------------------------------------------------------

typedef __attribute__((ext_vector_type(8))) short short8;   // 8 x bf16 (4 VGPR)
typedef __attribute__((ext_vector_type(4))) float float4e;  // 4 x fp32 acc
typedef __attribute__((ext_vector_type(16))) float f32x16;  // 32x32 acc

#define LOG2E 1.4426950408889634f

__device__ __forceinline__ ushort f2bf(float f) {
    union { float f; unsigned u; } v; v.f = f;
    unsigned r = v.u + 0x7FFF + ((v.u >> 16) & 1);
    return (ushort)(r >> 16);
}

// packed RNE fp32x2 -> bf16x2 (v_cvt_pk_bf16_f32); low 16 bits = first arg
__device__ __forceinline__ unsigned pk2bf(float a, float b) {
    float2 t; t.x = a; t.y = b;
    __hip_bfloat162 h = __float22bfloat162_rn(t);
    union { __hip_bfloat162 h; unsigned u; } cv; cv.h = h;
    return cv.u;
}

// raw v_exp_f32 (2^x), no libm wrapper
__device__ __forceinline__ float fexp2(float x) {
    return __builtin_amdgcn_exp2f(x);
}

// async 16B global -> LDS; LDS dest = wave-uniform base + lane*16.
__device__ __forceinline__ void async_cp16(const ushort* g, ushort* l) {
    __builtin_amdgcn_global_load_lds(
        (const __attribute__((address_space(1))) unsigned int*)g,
        (__attribute__((address_space(3))) unsigned int*)l,
        16, 0, 0);
}

// ===========================================================================
// Fused prep: blocks 0..575 = weight transposes (z = bid/144; Wq scaled by
// log2e for the exp2-domain attn); blocks 576..3647 = x fp32->bf16 cast.
// ===========================================================================
__global__ __launch_bounds__(256) void prep_fused(
    const float* __restrict__ xin, ushort* __restrict__ xout,
    const float* __restrict__ W0, const float* __restrict__ W1,
    const float* __restrict__ W2, const float* __restrict__ W3,
    ushort* __restrict__ WtBase)
{
    const int bid = blockIdx.x;
    const int tid = threadIdx.x;

    if (bid < 576) {
        __shared__ float t[64][65];
        const int z   = bid / 144;
        const int rem = bid - z * 144;
        const int by  = rem / 12, bx = rem - by * 12;
        const float* W = (z == 0) ? W0 : (z == 1) ? W1 : (z == 2) ? W2 : W3;
        const float scale = (z == 0) ? LOG2E : 1.0f;   // fold log2e into Wq
        ushort* Wt = WtBase + (size_t)z * (768u * 768u);

        const int c  = tid & 63;
        const int rg = tid >> 6;
        const int k0 = by * 64, n0 = bx * 64;
        #pragma unroll
        for (int r = 0; r < 16; ++r) {
            const int row = rg * 16 + r;
            t[row][c] = W[(size_t)(k0 + row) * 768 + n0 + c];
        }
        __syncthreads();
        #pragma unroll
        for (int r = 0; r < 16; ++r) {
            const int row = rg * 16 + r;
            Wt[(size_t)(n0 + row) * 768 + k0 + c] = f2bf(t[c][row] * scale);
        }
    } else {
        const int i = (bid - 576) * 256 + tid;      // < 786432 = XE/4
        float4 v = *(const float4*)&xin[(size_t)i * 4];
        ushort4 o;
        o.x = f2bf(v.x); o.y = f2bf(v.y); o.z = f2bf(v.z); o.w = f2bf(v.w);
        *(ushort4*)&xout[(size_t)i * 4] = o;
    }
}

// ===========================================================================
// V [4096x768] bf16 -> VT[b][h][d][s] bf16 (s-major per head).
// ===========================================================================
__global__ __launch_bounds__(256) void transpose_v(
    const ushort* __restrict__ Vb, ushort* __restrict__ VT)
{
    __shared__ ushort t[64][72];
    const int tid = threadIdx.x;
    const int b = blockIdx.z, h = blockIdx.y, s0 = blockIdx.x * 64;
    const int lr = tid >> 3;          // 0..31
    const int lc = (tid & 7) * 8;     // 0..56

    #pragma unroll
    for (int half = 0; half < 64; half += 32) {
        const int row = lr + half;
        *(uint4*)&t[row][lc] =
            *(const uint4*)&Vb[(size_t)(b * 2048 + s0 + row) * 768 + h * 64 + lc];
    }
    __syncthreads();
    #pragma unroll
    for (int half = 0; half < 64; half += 32) {
        const int d = lr + half;
        ushort tmp[8];
        #pragma unroll
        for (int i = 0; i < 8; ++i) tmp[i] = t[lc + i][d];
        *(uint4*)&VT[((size_t)(b * 12 + h) * 64 + d) * 2048 + s0 + lc] =
            *(const uint4*)tmp;
    }
}

// ===========================================================================
// Fused QKV GEMM: Out[M,2304] = x[M,768] @ [Wq|Wk|Wv]^T + [bq|bk|bv]
// 128x128 tile, BK=32, 4 waves 2x2, 16 accs/wave. 2-phase async pipeline.
// seg 0 bias (bq) scaled by log2e to match the scaled Wq.
// ===========================================================================
__global__ __launch_bounds__(256) void gemm_qkv_fused(
    const ushort* __restrict__ A, const ushort* __restrict__ Bt,
    const float* __restrict__ bq, const float* __restrict__ bk,
    const float* __restrict__ bv, ushort* __restrict__ Outbase)
{
    constexpr int K = 768;
    __shared__ ushort As[2][128][32];   // unpadded: required by global_load_lds
    __shared__ ushort Bs[2][128][32];

    const int tid  = threadIdx.x;
    const int w    = tid >> 6;
    const int lane = tid & 63;
    const int l16  = lane & 15;
    const int quad = lane >> 4;
    const int wr   = (w >> 1) * 64;
    const int wc   = (w & 1) * 64;
    const int row0 = blockIdx.y * 128, col0 = blockIdx.x * 128;

    const int r4 = lane >> 2;
    const int c8 = (lane & 3) * 8;

    float4e acc[4][4];
    #pragma unroll
    for (int mi = 0; mi < 4; ++mi)
        #pragma unroll
        for (int ni = 0; ni < 4; ++ni) acc[mi][ni] = (float4e){0.f,0.f,0.f,0.f};

    // prologue: stage K-step 0 into buf 0
    #pragma unroll
    for (int i = 0; i < 2; ++i) {
        const int rr = w * 32 + i * 16;
        async_cp16(&A [(size_t)(row0 + rr + r4) * K + c8], &As[0][rr][0]);
        async_cp16(&Bt[(size_t)(col0 + rr + r4) * K + c8], &Bs[0][rr][0]);
    }
    __syncthreads();   // implicit vmcnt(0) drain

    for (int k0 = 0; k0 < K; k0 += 32) {
        const int cur = (k0 >> 5) & 1;
        if (k0 + 32 < K) {            // issue next-step DMA before compute
            #pragma unroll
            for (int i = 0; i < 2; ++i) {
                const int rr = w * 32 + i * 16;
                async_cp16(&A [(size_t)(row0 + rr + r4) * K + k0 + 32 + c8],
                           &As[cur ^ 1][rr][0]);
                async_cp16(&Bt[(size_t)(col0 + rr + r4) * K + k0 + 32 + c8],
                           &Bs[cur ^ 1][rr][0]);
            }
        }

        short8 af[4], bf[4];
        #pragma unroll
        for (int i = 0; i < 4; ++i) {
            af[i] = *(const short8*)&As[cur][wr + i * 16 + l16][quad * 8];
            bf[i] = *(const short8*)&Bs[cur][wc + i * 16 + l16][quad * 8];
        }
        #pragma unroll
        for (int mi = 0; mi < 4; ++mi)
            #pragma unroll
            for (int ni = 0; ni < 4; ++ni)
                acc[mi][ni] = __builtin_amdgcn_mfma_f32_16x16x32_bf16(
                    af[mi], bf[ni], acc[mi][ni], 0, 0, 0);
        __syncthreads();  // next-step staged + this step's reads drained
    }

    const int seg = (col0 >= 1536) ? 2 : (col0 >= 768 ? 1 : 0);
    const float* bias = (seg == 0) ? bq : (seg == 1) ? bk : bv;
    const float bscale = (seg == 0) ? LOG2E : 1.0f;
    const int ncol0 = col0 - seg * 768 + wc;
    ushort* outp = Outbase + (size_t)seg * (4096u * 768u);

    #pragma unroll
    for (int ni = 0; ni < 4; ++ni) {
        const int col = ncol0 + ni * 16 + l16;
        const float bs = bias[col] * bscale;
        #pragma unroll
        for (int mi = 0; mi < 4; ++mi) {
            #pragma unroll
            for (int r = 0; r < 4; ++r) {
                const int row = row0 + wr + mi * 16 + quad * 4 + r;
                outp[(size_t)row * 768 + col] = f2bf(acc[mi][ni][r] + bs);
            }
        }
    }
}

// ===========================================================================
// Wo GEMM: C[4096,768](fp32) = ctx[4096,768] @ Wo^T + bo. 128x128 tile,
// 2-phase async DMA pipeline.
// ===========================================================================
__global__ __launch_bounds__(256) void gemm_wo_128(
    const ushort* __restrict__ A, const ushort* __restrict__ Bt,
    const float* __restrict__ bias, float* __restrict__ Cout)
{
    constexpr int K = 768, N = 768;
    __shared__ ushort As[2][128][32];
    __shared__ ushort Bs[2][128][32];

    const int tid  = threadIdx.x;
    const int w    = tid >> 6;
    const int lane = tid & 63;
    const int l16  = lane & 15;
    const int quad = lane >> 4;
    const int wr   = (w >> 1) * 64;
    const int wc   = (w & 1) * 64;
    const int row0 = blockIdx.y * 128, col0 = blockIdx.x * 128;

    const int r4 = lane >> 2;
    const int c8 = (lane & 3) * 8;

    float4e acc[4][4];
    #pragma unroll
    for (int mi = 0; mi < 4; ++mi)
        #pragma unroll
        for (int ni = 0; ni < 4; ++ni) acc[mi][ni] = (float4e){0.f,0.f,0.f,0.f};

    // prologue: stage K-step 0 into buf 0
    #pragma unroll
    for (int i = 0; i < 2; ++i) {
        const int rr = w * 32 + i * 16;
        async_cp16(&A [(size_t)(row0 + rr + r4) * K + c8], &As[0][rr][0]);
        async_cp16(&Bt[(size_t)(col0 + rr + r4) * K + c8], &Bs[0][rr][0]);
    }
    __syncthreads();

    for (int k0 = 0; k0 < K; k0 += 32) {
        const int cur = (k0 >> 5) & 1;
        if (k0 + 32 < K) {
            #pragma unroll
            for (int i = 0; i < 2; ++i) {
                const int rr = w * 32 + i * 16;
                async_cp16(&A [(size_t)(row0 + rr + r4) * K + k0 + 32 + c8],
                           &As[cur ^ 1][rr][0]);
                async_cp16(&Bt[(size_t)(col0 + rr + r4) * K + k0 + 32 + c8],
                           &Bs[cur ^ 1][rr][0]);
            }
        }

        short8 af[4], bf[4];
        #pragma unroll
        for (int i = 0; i < 4; ++i) {
            af[i] = *(const short8*)&As[cur][wr + i * 16 + l16][quad * 8];
            bf[i] = *(const short8*)&Bs[cur][wc + i * 16 + l16][quad * 8];
        }
        #pragma unroll
        for (int mi = 0; mi < 4; ++mi)
            #pragma unroll
            for (int ni = 0; ni < 4; ++ni)
                acc[mi][ni] = __builtin_amdgcn_mfma_f32_16x16x32_bf16(
                    af[mi], bf[ni], acc[mi][ni], 0, 0, 0);
        __syncthreads();
    }

    #pragma unroll
    for (int ni = 0; ni < 4; ++ni) {
        const int col = col0 + wc + ni * 16 + l16;
        const float bs = bias[col];
        #pragma unroll
        for (int mi = 0; mi < 4; ++mi) {
            #pragma unroll
            for (int r = 0; r < 4; ++r) {
                const int row = row0 + wr + mi * 16 + quad * 4 + r;
                Cout[(size_t)row * N + col] = acc[mi][ni][r] + bs;
            }
        }
    }
}

// ===========================================================================
// Flash attention, 32x32 MFMA, zero-shuffle softmax+PV. 512 thr = 8 waves.
// Log2-domain scores (Wq,bq pre-scaled) -> raw v_exp_f32; THR = 8*log2e.
// R24: V single-buffered (K double) -> LDS 50688 -> 3 blocks/CU.
// Per tile: issue K[t+1] | QK^T+softmax | barrier A (V[t]+K[t+1] staged) |
// PV | barrier B (V reads done) | issue V[t+1].
// Wave w: qg = w&1 (32 q), ks = w>>1 (32-key slice of 128-key tile).
// C-layout (HW-verified): col=l&31, row=(r&3)+8*(r>>2)+4*(l>>5).
// sigma_m(hi*8+j') = 4hi+(j'&3)+8*(j'>>2)+16m on BOTH PV operands.
// Swizzles (both-sides, rule 21): K granule ^(row&7); V granule ^(d&7).
// ===========================================================================
__global__ __launch_bounds__(512, 6) void attn_mfma(
    const ushort* __restrict__ Qg, const ushort* __restrict__ Kgl,
    const ushort* __restrict__ VT, ushort* __restrict__ Ctx)
{
    constexpr int S = 2048, D = 768;
    __shared__ union {
        struct {                      // main-loop stage buffers (swizzled)
            ushort Ks [2][128][64];   // [buf][key][16B-gran ^ (key&7)]
            ushort Vts[64][128];      // single buf: [d][16B-gran ^ (d&7)]
        } s;
        struct {                      // epilogue split-K combine buffers
            float Osc[6][2048];       // [slot][lane*32 + (g^(lane&7))*4 + e]
            float Msc[6][32];
            float Lsc[6][32];
        } c;
    } U;

    const int tid  = threadIdx.x;
    const int w    = tid >> 6;        // 0..7
    const int qg   = w & 1;           // query group (32 q)
    const int ks   = w >> 1;          // key slice 0..3 (32 of 128)
    const int lane = tid & 63;
    const int l31  = lane & 31;
    const int hi   = lane >> 5;
    const int b = blockIdx.z, h = blockIdx.y, q0 = blockIdx.x * 64;
    const size_t hc = (size_t)h * 64;

    // Q fragments (B-operand): yq[dc][j'] = Q[q][dc*16 + hi*8 + j']
    const size_t qrow = (size_t)(b * S + q0 + qg * 32 + l31) * D + hc + hi * 8;
    short8 yq[4];
    #pragma unroll
    for (int dc = 0; dc < 4; ++dc) yq[dc] = *(const short8*)&Qg[qrow + dc * 16];

    // ---- staging (rule 21: pre-swizzled global source, linear LDS dest) ----
    const int sr  = tid >> 3;                    // K row 0..63 (+64 2nd issue)
    const int kgr = (tid & 7) ^ (sr & 7);        // 16B granule of 8
    const ushort* srcK = &Kgl[(size_t)(b * S + sr) * D + hc + kgr * 8];
    const int vr  = tid >> 4;                    // V row 0..31 (+32 2nd issue)
    const int vgr = (tid & 15) ^ (vr & 7);       // 16B granule of 16
    const ushort* srcV = &VT[((size_t)(b * 12 + h) * 64 + vr) * 2048 + vgr * 8];
    ushort* dK0 = &U.s.Ks [0][w * 8][0];         // wave-uniform bases
    ushort* dK1 = &U.s.Ks [1][w * 8][0];
    ushort* dV  = &U.s.Vts[w * 4][0];

    // ---- loop-invariant swizzled read offsets (ushort units) ----
    int okf[4];                                  // K b128: row ks*32+l31
    #pragma unroll
    for (int dc = 0; dc < 4; ++dc)
        okf[dc] = (ks * 32 + l31) * 64 + ((dc * 2 + hi) ^ (l31 & 7)) * 8;
    int ovo[2][2][2];                            // V b64: [a][m][chunk]
    #pragma unroll
    for (int a = 0; a < 2; ++a)
        #pragma unroll
        for (int m = 0; m < 2; ++m)
            #pragma unroll
            for (int c2 = 0; c2 < 2; ++c2)
                ovo[a][m][c2] = (a * 32 + l31) * 128 +
                    ((ks * 4 + m * 2 + c2) ^ (l31 & 7)) * 8 + hi * 4;

    float m_ = -1e30f, l_ = 0.f;
    f32x16 oa0, oa1;
    #pragma unroll
    for (int i = 0; i < 16; ++i) { oa0[i] = 0.f; oa1[i] = 0.f; }

    // prologue: stage tile 0 (K into buf 0, V into single buf)
    async_cp16(srcK,                  dK0);
    async_cp16(srcK + (size_t)64 * D, dK0 + 64 * 64);
    async_cp16(srcV,                  dV);
    async_cp16(srcV + 32 * 2048,      dV + 32 * 128);
    __syncthreads();                  // implicit vmcnt(0) drain

    #pragma unroll 2
    for (int t = 0; t < 16; ++t) {
        const int cur = t & 1;
        const ushort* ksb = cur ? &U.s.Ks[1][0][0] : &U.s.Ks[0][0][0];
        const ushort* vsb = &U.s.Vts[0][0];

        if (t + 1 < 16) {             // 1: issue next K tile DMA
            const size_t kn = (size_t)(t + 1) * 128;
            ushort* dK = cur ? dK0 : dK1;
            async_cp16(srcK + kn * D,        dK);
            async_cp16(srcK + (kn + 64) * D, dK + 64 * 64);
        }

        // 2: scores S^T[32k x 32q] in log2 domain, 4 chained MFMAs
        f32x16 sa;
        #pragma unroll
        for (int i = 0; i < 16; ++i) sa[i] = 0.f;
        __builtin_amdgcn_s_setprio(1);
        #pragma unroll
        for (int dc = 0; dc < 4; ++dc) {
            const short8 xk = *(const short8*)&ksb[okf[dc]];
            sa = __builtin_amdgcn_mfma_f32_32x32x16_bf16(xk, yq[dc], sa, 0, 0, 0);
        }
        __builtin_amdgcn_s_setprio(0);

        // online softmax (log2 domain): 15 fmax + 1 shfl32
        float mx = sa[0];
        #pragma unroll
        for (int r = 1; r < 16; ++r) mx = fmaxf(mx, sa[r]);
        mx = fmaxf(mx, __shfl_xor(mx, 32, 64));

        // defer-max (T13): THR = 8*log2e -> P bounded by e^8.
        const bool full = !__all(mx - m_ <= 11.5415603f);
        if (full) {
            const float mn = fmaxf(m_, mx);
            const float alpha = fexp2(m_ - mn);    // first iter: 0
            l_ *= alpha;
            m_ = mn;
            #pragma unroll
            for (int i = 0; i < 16; ++i) { oa0[i] *= alpha; oa1[i] *= alpha; }
        }

        float p[16], ps = 0.f;
        #pragma unroll
        for (int r = 0; r < 16; ++r) {
            p[r] = fexp2(sa[r] - m_);              // bare v_exp_f32
            ps += p[r];
        }
        ps += __shfl_xor(ps, 32, 64);
        l_ += ps;

        __syncthreads();  // 3: barrier A -- V[t] staged; K[t+1] drained

        // PV B-operands: own p[] packed (slot j' = p[8m + j'])
        union { unsigned u[4]; short8 s8; } pa0, pa1;
        pa0.u[0] = pk2bf(p[0],  p[1]);  pa0.u[1] = pk2bf(p[2],  p[3]);
        pa0.u[2] = pk2bf(p[4],  p[5]);  pa0.u[3] = pk2bf(p[6],  p[7]);
        pa1.u[0] = pk2bf(p[8],  p[9]);  pa1.u[1] = pk2bf(p[10], p[11]);
        pa1.u[2] = pk2bf(p[12], p[13]); pa1.u[3] = pk2bf(p[14], p[15]);

        // 4: PV: O^T[64d x 32q] += V^T x P (4 MFMAs, 8 b64 V-reads)
        __builtin_amdgcn_s_setprio(1);
        {
            union { uint2 v2[2]; short8 s8; } xv;
            xv.v2[0] = *(const uint2*)&vsb[ovo[0][0][0]];
            xv.v2[1] = *(const uint2*)&vsb[ovo[0][0][1]];
            oa0 = __builtin_amdgcn_mfma_f32_32x32x16_bf16(xv.s8, pa0.s8, oa0, 0, 0, 0);
            xv.v2[0] = *(const uint2*)&vsb[ovo[0][1][0]];
            xv.v2[1] = *(const uint2*)&vsb[ovo[0][1][1]];
            oa0 = __builtin_amdgcn_mfma_f32_32x32x16_bf16(xv.s8, pa1.s8, oa0, 0, 0, 0);
            xv.v2[0] = *(const uint2*)&vsb[ovo[1][0][0]];
            xv.v2[1] = *(const uint2*)&vsb[ovo[1][0][1]];
            oa1 = __builtin_amdgcn_mfma_f32_32x32x16_bf16(xv.s8, pa0.s8, oa1, 0, 0, 0);
            xv.v2[0] = *(const uint2*)&vsb[ovo[1][1][0]];
            xv.v2[1] = *(const uint2*)&vsb[ovo[1][1][1]];
            oa1 = __builtin_amdgcn_mfma_f32_32x32x16_bf16(xv.s8, pa1.s8, oa1, 0, 0, 0);
        }
        __builtin_amdgcn_s_setprio(0);

        __syncthreads();  // 5: barrier B -- all waves done reading Vts

        if (t + 1 < 16) { // 6: issue next V tile DMA into the single buffer
            const size_t kn = (size_t)(t + 1) * 128;
            async_cp16(srcV + kn,             dV);
            async_cp16(srcV + kn + 32 * 2048, dV + 32 * 128);
        }
    }

    // ---- 4-way split-K combine (stage buffers dead; union reuse) ----
    if (ks > 0) {
        const int slot = (ks - 1) * 2 + qg;
        float* ob = &U.c.Osc[slot][lane * 32];
        #pragma unroll
        for (int g = 0; g < 4; ++g) {
            float4 v0, v1;
            v0.x = oa0[g * 4 + 0]; v0.y = oa0[g * 4 + 1];
            v0.z = oa0[g * 4 + 2]; v0.w = oa0[g * 4 + 3];
            v1.x = oa1[g * 4 + 0]; v1.y = oa1[g * 4 + 1];
            v1.z = oa1[g * 4 + 2]; v1.w = oa1[g * 4 + 3];
            *(float4*)&ob[(( g     ) ^ (lane & 7)) * 4] = v0;
            *(float4*)&ob[(((g + 4)) ^ (lane & 7)) * 4] = v1;
        }
        if (hi == 0) {
            U.c.Msc[slot][l31] = m_;
            U.c.Lsc[slot][l31] = l_;
        }
    }
    __syncthreads();
    if (ks == 0) {
        const float m1 = U.c.Msc[qg][l31];
        const float m2 = U.c.Msc[2 + qg][l31];
        const float m3 = U.c.Msc[4 + qg][l31];
        const float M  = fmaxf(fmaxf(m_, m1), fmaxf(m2, m3));
        const float a0 = fexp2(m_ - M), a1 = fexp2(m1 - M),
                    a2 = fexp2(m2 - M), a3 = fexp2(m3 - M);
        const float l1 = U.c.Lsc[qg][l31];
        const float l2 = U.c.Lsc[2 + qg][l31];
        const float l3 = U.c.Lsc[4 + qg][l31];
        const float inv = 1.0f / (l_ * a0 + l1 * a1 + l2 * a2 + l3 * a3);

        float o[32];
        #pragma unroll
        for (int i = 0; i < 16; ++i) { o[i] = oa0[i] * a0; o[16 + i] = oa1[i] * a0; }
        #pragma unroll
        for (int s = 0; s < 3; ++s) {
            const float as = (s == 0) ? a1 : (s == 1) ? a2 : a3;
            const float* ob = &U.c.Osc[s * 2 + qg][lane * 32];
            #pragma unroll
            for (int gg = 0; gg < 8; ++gg) {
                const float4 v = *(const float4*)&ob[(gg ^ (lane & 7)) * 4];
                o[gg * 4 + 0] += v.x * as;
                o[gg * 4 + 1] += v.y * as;
                o[gg * 4 + 2] += v.z * as;
                o[gg * 4 + 3] += v.w * as;
            }
        }

        // lane owns q = q0+qg*32+l31; d = a*32 + 8*rq + 4*hi + e
        const size_t crow = (size_t)(b * S + q0 + qg * 32 + l31) * D + hc;
        #pragma unroll
        for (int a = 0; a < 2; ++a)
            #pragma unroll
            for (int rq = 0; rq < 4; ++rq) {
                const int base = a * 16 + rq * 4;
                uint2 ov;
                ov.x = pk2bf(o[base + 0] * inv, o[base + 1] * inv);
                ov.y = pk2bf(o[base + 2] * inv, o[base + 3] * inv);
                *(uint2*)&Ctx[crow + a * 32 + rq * 8 + hi * 4] = ov;
            }
    }
}

// ===========================================================================
// Launch
// ===========================================================================
extern "C" void kernel_launch(void* const* d_in, const int* in_sizes, int n_in,
                              void* d_out, int out_size, void* d_ws, size_t ws_size,
                              hipStream_t stream)
{
    const float* x  = (const float*)d_in[0];
    const float* Wq = (const float*)d_in[1];
    const float* bq = (const float*)d_in[2];
    const float* Wk = (const float*)d_in[3];
    const float* bk = (const float*)d_in[4];
    const float* Wv = (const float*)d_in[5];
    const float* bv = (const float*)d_in[6];
    const float* Wo = (const float*)d_in[7];
    const float* bo = (const float*)d_in[8];

    const int M = 4096, D = 768;
    const size_t XE = (size_t)M * D;     // 3,145,728
    const size_t WE = (size_t)D * D;     //   589,824

    ushort* xb   = (ushort*)d_ws;
    ushort* wtq  = xb   + XE;            // wtq/wtk/wtv/wto contiguous
    ushort* wto  = wtq  + 3 * WE;
    ushort* qb   = wto  + WE;            // qb/kb/vb contiguous
    ushort* kb   = qb   + XE;
    ushort* vb   = kb   + XE;
    ushort* ctxb = vb   + XE;
    ushort* vt   = xb;                   // reuse xb (dead after fused GEMM)

    // fused prep: 576 weight-transpose blocks + 3072 cast blocks
    prep_fused<<<dim3(576 + 3072), 256, 0, stream>>>(
        x, xb, Wq, Wk, Wv, Wo, wtq);

    gemm_qkv_fused<<<dim3(2304 / 128, 4096 / 128), 256, 0, stream>>>(
        xb, wtq, bq, bk, bv, qb);

    transpose_v<<<dim3(32, 12, 2), 256, 0, stream>>>(vb, vt);

    attn_mfma<<<dim3(2048 / 64, 12, 2), 512, 0, stream>>>(qb, kb, vt, ctxb);

    gemm_wo_128<<<dim3(768 / 128, 4096 / 128), 256, 0, stream>>>(
        ctxb, wto, bo, (float*)d_out);
}

// Round 11
// 180.994 us; speedup vs baseline: 1.3199x; 1.3199x over previous
//
#include <hip/hip_runtime.h>
#include <hip/hip_bf16.h>

// ---------------------------------------------------------------------------
// B=2, S=2048, D=768, H=12, Dh=64. M = B*S = 4096.
// R25: R24 with launch_bounds fixed (512,6)->(512,4). R24's 109us regression
// was SCRATCH SPILL: forcing 6 waves/EU caps VGPR at 64 (m69 occupancy
// steps), compiler spilled accumulators (VGPR 60->40, WRITE_SIZE 6->52MB,
// FETCH 52->220MB). Same mechanism explains R21's failure. At (512,4) the
// kernel compiles at ~60 VGPR (R19/R20/R23 evidence) -- under the 64-VGPR
// step -- so LDS 50688 alone sets residency: 3 blocks/CU, 24 waves/CU.
// attn structure (single-buffered V, 2 barriers/tile), GEMMs, prep =
// R24/R23 verbatim.
// ---------------------------------------------------------------------------

typedef __attribute__((ext_vector_type(8))) short short8;   // 8 x bf16 (4 VGPR)
typedef __attribute__((ext_vector_type(4))) float float4e;  // 4 x fp32 acc
typedef __attribute__((ext_vector_type(16))) float f32x16;  // 32x32 acc

#define LOG2E 1.4426950408889634f

__device__ __forceinline__ ushort f2bf(float f) {
    union { float f; unsigned u; } v; v.f = f;
    unsigned r = v.u + 0x7FFF + ((v.u >> 16) & 1);
    return (ushort)(r >> 16);
}

// packed RNE fp32x2 -> bf16x2 (v_cvt_pk_bf16_f32); low 16 bits = first arg
__device__ __forceinline__ unsigned pk2bf(float a, float b) {
    float2 t; t.x = a; t.y = b;
    __hip_bfloat162 h = __float22bfloat162_rn(t);
    union { __hip_bfloat162 h; unsigned u; } cv; cv.h = h;
    return cv.u;
}

// raw v_exp_f32 (2^x), no libm wrapper
__device__ __forceinline__ float fexp2(float x) {
    return __builtin_amdgcn_exp2f(x);
}

// async 16B global -> LDS; LDS dest = wave-uniform base + lane*16.
__device__ __forceinline__ void async_cp16(const ushort* g, ushort* l) {
    __builtin_amdgcn_global_load_lds(
        (const __attribute__((address_space(1))) unsigned int*)g,
        (__attribute__((address_space(3))) unsigned int*)l,
        16, 0, 0);
}

// ===========================================================================
// Fused prep: blocks 0..575 = weight transposes (z = bid/144; Wq scaled by
// log2e for the exp2-domain attn); blocks 576..3647 = x fp32->bf16 cast.
// ===========================================================================
__global__ __launch_bounds__(256) void prep_fused(
    const float* __restrict__ xin, ushort* __restrict__ xout,
    const float* __restrict__ W0, const float* __restrict__ W1,
    const float* __restrict__ W2, const float* __restrict__ W3,
    ushort* __restrict__ WtBase)
{
    const int bid = blockIdx.x;
    const int tid = threadIdx.x;

    if (bid < 576) {
        __shared__ float t[64][65];
        const int z   = bid / 144;
        const int rem = bid - z * 144;
        const int by  = rem / 12, bx = rem - by * 12;
        const float* W = (z == 0) ? W0 : (z == 1) ? W1 : (z == 2) ? W2 : W3;
        const float scale = (z == 0) ? LOG2E : 1.0f;   // fold log2e into Wq
        ushort* Wt = WtBase + (size_t)z * (768u * 768u);

        const int c  = tid & 63;
        const int rg = tid >> 6;
        const int k0 = by * 64, n0 = bx * 64;
        #pragma unroll
        for (int r = 0; r < 16; ++r) {
            const int row = rg * 16 + r;
            t[row][c] = W[(size_t)(k0 + row) * 768 + n0 + c];
        }
        __syncthreads();
        #pragma unroll
        for (int r = 0; r < 16; ++r) {
            const int row = rg * 16 + r;
            Wt[(size_t)(n0 + row) * 768 + k0 + c] = f2bf(t[c][row] * scale);
        }
    } else {
        const int i = (bid - 576) * 256 + tid;      // < 786432 = XE/4
        float4 v = *(const float4*)&xin[(size_t)i * 4];
        ushort4 o;
        o.x = f2bf(v.x); o.y = f2bf(v.y); o.z = f2bf(v.z); o.w = f2bf(v.w);
        *(ushort4*)&xout[(size_t)i * 4] = o;
    }
}

// ===========================================================================
// V [4096x768] bf16 -> VT[b][h][d][s] bf16 (s-major per head).
// ===========================================================================
__global__ __launch_bounds__(256) void transpose_v(
    const ushort* __restrict__ Vb, ushort* __restrict__ VT)
{
    __shared__ ushort t[64][72];
    const int tid = threadIdx.x;
    const int b = blockIdx.z, h = blockIdx.y, s0 = blockIdx.x * 64;
    const int lr = tid >> 3;          // 0..31
    const int lc = (tid & 7) * 8;     // 0..56

    #pragma unroll
    for (int half = 0; half < 64; half += 32) {
        const int row = lr + half;
        *(uint4*)&t[row][lc] =
            *(const uint4*)&Vb[(size_t)(b * 2048 + s0 + row) * 768 + h * 64 + lc];
    }
    __syncthreads();
    #pragma unroll
    for (int half = 0; half < 64; half += 32) {
        const int d = lr + half;
        ushort tmp[8];
        #pragma unroll
        for (int i = 0; i < 8; ++i) tmp[i] = t[lc + i][d];
        *(uint4*)&VT[((size_t)(b * 12 + h) * 64 + d) * 2048 + s0 + lc] =
            *(const uint4*)tmp;
    }
}

// ===========================================================================
// Fused QKV GEMM: Out[M,2304] = x[M,768] @ [Wq|Wk|Wv]^T + [bq|bk|bv]
// 128x128 tile, BK=32, 4 waves 2x2, 16 accs/wave. 2-phase async pipeline.
// seg 0 bias (bq) scaled by log2e to match the scaled Wq.
// ===========================================================================
__global__ __launch_bounds__(256) void gemm_qkv_fused(
    const ushort* __restrict__ A, const ushort* __restrict__ Bt,
    const float* __restrict__ bq, const float* __restrict__ bk,
    const float* __restrict__ bv, ushort* __restrict__ Outbase)
{
    constexpr int K = 768;
    __shared__ ushort As[2][128][32];   // unpadded: required by global_load_lds
    __shared__ ushort Bs[2][128][32];

    const int tid  = threadIdx.x;
    const int w    = tid >> 6;
    const int lane = tid & 63;
    const int l16  = lane & 15;
    const int quad = lane >> 4;
    const int wr   = (w >> 1) * 64;
    const int wc   = (w & 1) * 64;
    const int row0 = blockIdx.y * 128, col0 = blockIdx.x * 128;

    const int r4 = lane >> 2;
    const int c8 = (lane & 3) * 8;

    float4e acc[4][4];
    #pragma unroll
    for (int mi = 0; mi < 4; ++mi)
        #pragma unroll
        for (int ni = 0; ni < 4; ++ni) acc[mi][ni] = (float4e){0.f,0.f,0.f,0.f};

    // prologue: stage K-step 0 into buf 0
    #pragma unroll
    for (int i = 0; i < 2; ++i) {
        const int rr = w * 32 + i * 16;
        async_cp16(&A [(size_t)(row0 + rr + r4) * K + c8], &As[0][rr][0]);
        async_cp16(&Bt[(size_t)(col0 + rr + r4) * K + c8], &Bs[0][rr][0]);
    }
    __syncthreads();   // implicit vmcnt(0) drain

    for (int k0 = 0; k0 < K; k0 += 32) {
        const int cur = (k0 >> 5) & 1;
        if (k0 + 32 < K) {            // issue next-step DMA before compute
            #pragma unroll
            for (int i = 0; i < 2; ++i) {
                const int rr = w * 32 + i * 16;
                async_cp16(&A [(size_t)(row0 + rr + r4) * K + k0 + 32 + c8],
                           &As[cur ^ 1][rr][0]);
                async_cp16(&Bt[(size_t)(col0 + rr + r4) * K + k0 + 32 + c8],
                           &Bs[cur ^ 1][rr][0]);
            }
        }

        short8 af[4], bf[4];
        #pragma unroll
        for (int i = 0; i < 4; ++i) {
            af[i] = *(const short8*)&As[cur][wr + i * 16 + l16][quad * 8];
            bf[i] = *(const short8*)&Bs[cur][wc + i * 16 + l16][quad * 8];
        }
        #pragma unroll
        for (int mi = 0; mi < 4; ++mi)
            #pragma unroll
            for (int ni = 0; ni < 4; ++ni)
                acc[mi][ni] = __builtin_amdgcn_mfma_f32_16x16x32_bf16(
                    af[mi], bf[ni], acc[mi][ni], 0, 0, 0);
        __syncthreads();  // next-step staged + this step's reads drained
    }

    const int seg = (col0 >= 1536) ? 2 : (col0 >= 768 ? 1 : 0);
    const float* bias = (seg == 0) ? bq : (seg == 1) ? bk : bv;
    const float bscale = (seg == 0) ? LOG2E : 1.0f;
    const int ncol0 = col0 - seg * 768 + wc;
    ushort* outp = Outbase + (size_t)seg * (4096u * 768u);

    #pragma unroll
    for (int ni = 0; ni < 4; ++ni) {
        const int col = ncol0 + ni * 16 + l16;
        const float bs = bias[col] * bscale;
        #pragma unroll
        for (int mi = 0; mi < 4; ++mi) {
            #pragma unroll
            for (int r = 0; r < 4; ++r) {
                const int row = row0 + wr + mi * 16 + quad * 4 + r;
                outp[(size_t)row * 768 + col] = f2bf(acc[mi][ni][r] + bs);
            }
        }
    }
}

// ===========================================================================
// Wo GEMM: C[4096,768](fp32) = ctx[4096,768] @ Wo^T + bo. 128x128 tile,
// 2-phase async DMA pipeline.
// ===========================================================================
__global__ __launch_bounds__(256) void gemm_wo_128(
    const ushort* __restrict__ A, const ushort* __restrict__ Bt,
    const float* __restrict__ bias, float* __restrict__ Cout)
{
    constexpr int K = 768, N = 768;
    __shared__ ushort As[2][128][32];
    __shared__ ushort Bs[2][128][32];

    const int tid  = threadIdx.x;
    const int w    = tid >> 6;
    const int lane = tid & 63;
    const int l16  = lane & 15;
    const int quad = lane >> 4;
    const int wr   = (w >> 1) * 64;
    const int wc   = (w & 1) * 64;
    const int row0 = blockIdx.y * 128, col0 = blockIdx.x * 128;

    const int r4 = lane >> 2;
    const int c8 = (lane & 3) * 8;

    float4e acc[4][4];
    #pragma unroll
    for (int mi = 0; mi < 4; ++mi)
        #pragma unroll
        for (int ni = 0; ni < 4; ++ni) acc[mi][ni] = (float4e){0.f,0.f,0.f,0.f};

    // prologue: stage K-step 0 into buf 0
    #pragma unroll
    for (int i = 0; i < 2; ++i) {
        const int rr = w * 32 + i * 16;
        async_cp16(&A [(size_t)(row0 + rr + r4) * K + c8], &As[0][rr][0]);
        async_cp16(&Bt[(size_t)(col0 + rr + r4) * K + c8], &Bs[0][rr][0]);
    }
    __syncthreads();

    for (int k0 = 0; k0 < K; k0 += 32) {
        const int cur = (k0 >> 5) & 1;
        if (k0 + 32 < K) {
            #pragma unroll
            for (int i = 0; i < 2; ++i) {
                const int rr = w * 32 + i * 16;
                async_cp16(&A [(size_t)(row0 + rr + r4) * K + k0 + 32 + c8],
                           &As[cur ^ 1][rr][0]);
                async_cp16(&Bt[(size_t)(col0 + rr + r4) * K + k0 + 32 + c8],
                           &Bs[cur ^ 1][rr][0]);
            }
        }

        short8 af[4], bf[4];
        #pragma unroll
        for (int i = 0; i < 4; ++i) {
            af[i] = *(const short8*)&As[cur][wr + i * 16 + l16][quad * 8];
            bf[i] = *(const short8*)&Bs[cur][wc + i * 16 + l16][quad * 8];
        }
        #pragma unroll
        for (int mi = 0; mi < 4; ++mi)
            #pragma unroll
            for (int ni = 0; ni < 4; ++ni)
                acc[mi][ni] = __builtin_amdgcn_mfma_f32_16x16x32_bf16(
                    af[mi], bf[ni], acc[mi][ni], 0, 0, 0);
        __syncthreads();
    }

    #pragma unroll
    for (int ni = 0; ni < 4; ++ni) {
        const int col = col0 + wc + ni * 16 + l16;
        const float bs = bias[col];
        #pragma unroll
        for (int mi = 0; mi < 4; ++mi) {
            #pragma unroll
            for (int r = 0; r < 4; ++r) {
                const int row = row0 + wr + mi * 16 + quad * 4 + r;
                Cout[(size_t)row * N + col] = acc[mi][ni][r] + bs;
            }
        }
    }
}

// ===========================================================================
// Flash attention, 32x32 MFMA, zero-shuffle softmax+PV. 512 thr = 8 waves.
// Log2-domain scores (Wq,bq pre-scaled) -> raw v_exp_f32; THR = 8*log2e.
// V single-buffered (K double) -> LDS 50688; launch_bounds (512,4) so the
// compiler keeps its natural ~60 VGPR (<= 64 step) -> 3 blocks/CU without
// spill (R24's (512,6) forced spill-to-scratch: VGPR 40, WRITE 52MB).
// Per tile: issue K[t+1] | QK^T+softmax | barrier A (V[t]+K[t+1] staged) |
// PV | barrier B (V reads done) | issue V[t+1].
// Wave w: qg = w&1 (32 q), ks = w>>1 (32-key slice of 128-key tile).
// C-layout (HW-verified): col=l&31, row=(r&3)+8*(r>>2)+4*(l>>5).
// sigma_m(hi*8+j') = 4hi+(j'&3)+8*(j'>>2)+16m on BOTH PV operands.
// Swizzles (both-sides, rule 21): K granule ^(row&7); V granule ^(d&7).
// ===========================================================================
__global__ __launch_bounds__(512, 4) void attn_mfma(
    const ushort* __restrict__ Qg, const ushort* __restrict__ Kgl,
    const ushort* __restrict__ VT, ushort* __restrict__ Ctx)
{
    constexpr int S = 2048, D = 768;
    __shared__ union {
        struct {                      // main-loop stage buffers (swizzled)
            ushort Ks [2][128][64];   // [buf][key][16B-gran ^ (key&7)]
            ushort Vts[64][128];      // single buf: [d][16B-gran ^ (d&7)]
        } s;
        struct {                      // epilogue split-K combine buffers
            float Osc[6][2048];       // [slot][lane*32 + (g^(lane&7))*4 + e]
            float Msc[6][32];
            float Lsc[6][32];
        } c;
    } U;

    const int tid  = threadIdx.x;
    const int w    = tid >> 6;        // 0..7
    const int qg   = w & 1;           // query group (32 q)
    const int ks   = w >> 1;          // key slice 0..3 (32 of 128)
    const int lane = tid & 63;
    const int l31  = lane & 31;
    const int hi   = lane >> 5;
    const int b = blockIdx.z, h = blockIdx.y, q0 = blockIdx.x * 64;
    const size_t hc = (size_t)h * 64;

    // Q fragments (B-operand): yq[dc][j'] = Q[q][dc*16 + hi*8 + j']
    const size_t qrow = (size_t)(b * S + q0 + qg * 32 + l31) * D + hc + hi * 8;
    short8 yq[4];
    #pragma unroll
    for (int dc = 0; dc < 4; ++dc) yq[dc] = *(const short8*)&Qg[qrow + dc * 16];

    // ---- staging (rule 21: pre-swizzled global source, linear LDS dest) ----
    const int sr  = tid >> 3;                    // K row 0..63 (+64 2nd issue)
    const int kgr = (tid & 7) ^ (sr & 7);        // 16B granule of 8
    const ushort* srcK = &Kgl[(size_t)(b * S + sr) * D + hc + kgr * 8];
    const int vr  = tid >> 4;                    // V row 0..31 (+32 2nd issue)
    const int vgr = (tid & 15) ^ (vr & 7);       // 16B granule of 16
    const ushort* srcV = &VT[((size_t)(b * 12 + h) * 64 + vr) * 2048 + vgr * 8];
    ushort* dK0 = &U.s.Ks [0][w * 8][0];         // wave-uniform bases
    ushort* dK1 = &U.s.Ks [1][w * 8][0];
    ushort* dV  = &U.s.Vts[w * 4][0];

    // ---- loop-invariant swizzled read offsets (ushort units) ----
    int okf[4];                                  // K b128: row ks*32+l31
    #pragma unroll
    for (int dc = 0; dc < 4; ++dc)
        okf[dc] = (ks * 32 + l31) * 64 + ((dc * 2 + hi) ^ (l31 & 7)) * 8;
    int ovo[2][2][2];                            // V b64: [a][m][chunk]
    #pragma unroll
    for (int a = 0; a < 2; ++a)
        #pragma unroll
        for (int m = 0; m < 2; ++m)
            #pragma unroll
            for (int c2 = 0; c2 < 2; ++c2)
                ovo[a][m][c2] = (a * 32 + l31) * 128 +
                    ((ks * 4 + m * 2 + c2) ^ (l31 & 7)) * 8 + hi * 4;

    float m_ = -1e30f, l_ = 0.f;
    f32x16 oa0, oa1;
    #pragma unroll
    for (int i = 0; i < 16; ++i) { oa0[i] = 0.f; oa1[i] = 0.f; }

    // prologue: stage tile 0 (K into buf 0, V into single buf)
    async_cp16(srcK,                  dK0);
    async_cp16(srcK + (size_t)64 * D, dK0 + 64 * 64);
    async_cp16(srcV,                  dV);
    async_cp16(srcV + 32 * 2048,      dV + 32 * 128);
    __syncthreads();                  // implicit vmcnt(0) drain

    #pragma unroll 2
    for (int t = 0; t < 16; ++t) {
        const int cur = t & 1;
        const ushort* ksb = cur ? &U.s.Ks[1][0][0] : &U.s.Ks[0][0][0];
        const ushort* vsb = &U.s.Vts[0][0];

        if (t + 1 < 16) {             // 1: issue next K tile DMA
            const size_t kn = (size_t)(t + 1) * 128;
            ushort* dK = cur ? dK0 : dK1;
            async_cp16(srcK + kn * D,        dK);
            async_cp16(srcK + (kn + 64) * D, dK + 64 * 64);
        }

        // 2: scores S^T[32k x 32q] in log2 domain, 4 chained MFMAs
        f32x16 sa;
        #pragma unroll
        for (int i = 0; i < 16; ++i) sa[i] = 0.f;
        __builtin_amdgcn_s_setprio(1);
        #pragma unroll
        for (int dc = 0; dc < 4; ++dc) {
            const short8 xk = *(const short8*)&ksb[okf[dc]];
            sa = __builtin_amdgcn_mfma_f32_32x32x16_bf16(xk, yq[dc], sa, 0, 0, 0);
        }
        __builtin_amdgcn_s_setprio(0);

        // online softmax (log2 domain): 15 fmax + 1 shfl32
        float mx = sa[0];
        #pragma unroll
        for (int r = 1; r < 16; ++r) mx = fmaxf(mx, sa[r]);
        mx = fmaxf(mx, __shfl_xor(mx, 32, 64));

        // defer-max (T13): THR = 8*log2e -> P bounded by e^8.
        const bool full = !__all(mx - m_ <= 11.5415603f);
        if (full) {
            const float mn = fmaxf(m_, mx);
            const float alpha = fexp2(m_ - mn);    // first iter: 0
            l_ *= alpha;
            m_ = mn;
            #pragma unroll
            for (int i = 0; i < 16; ++i) { oa0[i] *= alpha; oa1[i] *= alpha; }
        }

        float p[16], ps = 0.f;
        #pragma unroll
        for (int r = 0; r < 16; ++r) {
            p[r] = fexp2(sa[r] - m_);              // bare v_exp_f32
            ps += p[r];
        }
        ps += __shfl_xor(ps, 32, 64);
        l_ += ps;

        __syncthreads();  // 3: barrier A -- V[t] staged; K[t+1] drained

        // PV B-operands: own p[] packed (slot j' = p[8m + j'])
        union { unsigned u[4]; short8 s8; } pa0, pa1;
        pa0.u[0] = pk2bf(p[0],  p[1]);  pa0.u[1] = pk2bf(p[2],  p[3]);
        pa0.u[2] = pk2bf(p[4],  p[5]);  pa0.u[3] = pk2bf(p[6],  p[7]);
        pa1.u[0] = pk2bf(p[8],  p[9]);  pa1.u[1] = pk2bf(p[10], p[11]);
        pa1.u[2] = pk2bf(p[12], p[13]); pa1.u[3] = pk2bf(p[14], p[15]);

        // 4: PV: O^T[64d x 32q] += V^T x P (4 MFMAs, 8 b64 V-reads)
        __builtin_amdgcn_s_setprio(1);
        {
            union { uint2 v2[2]; short8 s8; } xv;
            xv.v2[0] = *(const uint2*)&vsb[ovo[0][0][0]];
            xv.v2[1] = *(const uint2*)&vsb[ovo[0][0][1]];
            oa0 = __builtin_amdgcn_mfma_f32_32x32x16_bf16(xv.s8, pa0.s8, oa0, 0, 0, 0);
            xv.v2[0] = *(const uint2*)&vsb[ovo[0][1][0]];
            xv.v2[1] = *(const uint2*)&vsb[ovo[0][1][1]];
            oa0 = __builtin_amdgcn_mfma_f32_32x32x16_bf16(xv.s8, pa1.s8, oa0, 0, 0, 0);
            xv.v2[0] = *(const uint2*)&vsb[ovo[1][0][0]];
            xv.v2[1] = *(const uint2*)&vsb[ovo[1][0][1]];
            oa1 = __builtin_amdgcn_mfma_f32_32x32x16_bf16(xv.s8, pa0.s8, oa1, 0, 0, 0);
            xv.v2[0] = *(const uint2*)&vsb[ovo[1][1][0]];
            xv.v2[1] = *(const uint2*)&vsb[ovo[1][1][1]];
            oa1 = __builtin_amdgcn_mfma_f32_32x32x16_bf16(xv.s8, pa1.s8, oa1, 0, 0, 0);
        }
        __builtin_amdgcn_s_setprio(0);

        __syncthreads();  // 5: barrier B -- all waves done reading Vts

        if (t + 1 < 16) { // 6: issue next V tile DMA into the single buffer
            const size_t kn = (size_t)(t + 1) * 128;
            async_cp16(srcV + kn,             dV);
            async_cp16(srcV + kn + 32 * 2048, dV + 32 * 128);
        }
    }

    // ---- 4-way split-K combine (stage buffers dead; union reuse) ----
    if (ks > 0) {
        const int slot = (ks - 1) * 2 + qg;
        float* ob = &U.c.Osc[slot][lane * 32];
        #pragma unroll
        for (int g = 0; g < 4; ++g) {
            float4 v0, v1;
            v0.x = oa0[g * 4 + 0]; v0.y = oa0[g * 4 + 1];
            v0.z = oa0[g * 4 + 2]; v0.w = oa0[g * 4 + 3];
            v1.x = oa1[g * 4 + 0]; v1.y = oa1[g * 4 + 1];
            v1.z = oa1[g * 4 + 2]; v1.w = oa1[g * 4 + 3];
            *(float4*)&ob[(( g     ) ^ (lane & 7)) * 4] = v0;
            *(float4*)&ob[(((g + 4)) ^ (lane & 7)) * 4] = v1;
        }
        if (hi == 0) {
            U.c.Msc[slot][l31] = m_;
            U.c.Lsc[slot][l31] = l_;
        }
    }
    __syncthreads();
    if (ks == 0) {
        const float m1 = U.c.Msc[qg][l31];
        const float m2 = U.c.Msc[2 + qg][l31];
        const float m3 = U.c.Msc[4 + qg][l31];
        const float M  = fmaxf(fmaxf(m_, m1), fmaxf(m2, m3));
        const float a0 = fexp2(m_ - M), a1 = fexp2(m1 - M),
                    a2 = fexp2(m2 - M), a3 = fexp2(m3 - M);
        const float l1 = U.c.Lsc[qg][l31];
        const float l2 = U.c.Lsc[2 + qg][l31];
        const float l3 = U.c.Lsc[4 + qg][l31];
        const float inv = 1.0f / (l_ * a0 + l1 * a1 + l2 * a2 + l3 * a3);

        float o[32];
        #pragma unroll
        for (int i = 0; i < 16; ++i) { o[i] = oa0[i] * a0; o[16 + i] = oa1[i] * a0; }
        #pragma unroll
        for (int s = 0; s < 3; ++s) {
            const float as = (s == 0) ? a1 : (s == 1) ? a2 : a3;
            const float* ob = &U.c.Osc[s * 2 + qg][lane * 32];
            #pragma unroll
            for (int gg = 0; gg < 8; ++gg) {
                const float4 v = *(const float4*)&ob[(gg ^ (lane & 7)) * 4];
                o[gg * 4 + 0] += v.x * as;
                o[gg * 4 + 1] += v.y * as;
                o[gg * 4 + 2] += v.z * as;
                o[gg * 4 + 3] += v.w * as;
            }
        }

        // lane owns q = q0+qg*32+l31; d = a*32 + 8*rq + 4*hi + e
        const size_t crow = (size_t)(b * S + q0 + qg * 32 + l31) * D + hc;
        #pragma unroll
        for (int a = 0; a < 2; ++a)
            #pragma unroll
            for (int rq = 0; rq < 4; ++rq) {
                const int base = a * 16 + rq * 4;
                uint2 ov;
                ov.x = pk2bf(o[base + 0] * inv, o[base + 1] * inv);
                ov.y = pk2bf(o[base + 2] * inv, o[base + 3] * inv);
                *(uint2*)&Ctx[crow + a * 32 + rq * 8 + hi * 4] = ov;
            }
    }
}

// ===========================================================================
// Launch
// ===========================================================================
extern "C" void kernel_launch(void* const* d_in, const int* in_sizes, int n_in,
                              void* d_out, int out_size, void* d_ws, size_t ws_size,
                              hipStream_t stream)
{
    const float* x  = (const float*)d_in[0];
    const float* Wq = (const float*)d_in[1];
    const float* bq = (const float*)d_in[2];
    const float* Wk = (const float*)d_in[3];
    const float* bk = (const float*)d_in[4];
    const float* Wv = (const float*)d_in[5];
    const float* bv = (const float*)d_in[6];
    const float* Wo = (const float*)d_in[7];
    const float* bo = (const float*)d_in[8];

    const int M = 4096, D = 768;
    const size_t XE = (size_t)M * D;     // 3,145,728
    const size_t WE = (size_t)D * D;     //   589,824

    ushort* xb   = (ushort*)d_ws;
    ushort* wtq  = xb   + XE;            // wtq/wtk/wtv/wto contiguous
    ushort* wto  = wtq  + 3 * WE;
    ushort* qb   = wto  + WE;            // qb/kb/vb contiguous
    ushort* kb   = qb   + XE;
    ushort* vb   = kb   + XE;
    ushort* ctxb = vb   + XE;
    ushort* vt   = xb;                   // reuse xb (dead after fused GEMM)

    // fused prep: 576 weight-transpose blocks + 3072 cast blocks
    prep_fused<<<dim3(576 + 3072), 256, 0, stream>>>(
        x, xb, Wq, Wk, Wv, Wo, wtq);

    gemm_qkv_fused<<<dim3(2304 / 128, 4096 / 128), 256, 0, stream>>>(
        xb, wtq, bq, bk, bv, qb);

    transpose_v<<<dim3(32, 12, 2), 256, 0, stream>>>(vb, vt);

    attn_mfma<<<dim3(2048 / 64, 12, 2), 512, 0, stream>>>(qb, kb, vt, ctxb);

    gemm_wo_128<<<dim3(768 / 128, 4096 / 128), 256, 0, stream>>>(
        ctxb, wto, bo, (float*)d_out);
}

// Round 12
// 175.499 us; speedup vs baseline: 1.3613x; 1.0313x over previous
//
#include <hip/hip_runtime.h>
#include <hip/hip_bf16.h>

// ---------------------------------------------------------------------------
// B=2, S=2048, D=768, H=12, Dh=64. M = B*S = 4096.
// R26: attn reverted to R23 exact (55.4us proven; R24/R25's single-buffered
// V + extra barrier never beat it -- occupancy lever exhausted).
// transpose_v ELIMINATED: gemm_qkv seg==2 blocks transpose their V-tile
// in LDS (union'd with dead stage buffers, granule^(cl&15) swizzle) and
// write VT[b][h][d][s] directly as contiguous 128B/thread chunks --
// removes 25MB HBM round-trip + one launch (R17's failure was the direct
// per-lane scatter, not fusion per se; this keeps wave-level coalescing).
// vt gets its own workspace slot (gemm_qkv reads xb concurrently).
// ---------------------------------------------------------------------------

typedef __attribute__((ext_vector_type(8))) short short8;   // 8 x bf16 (4 VGPR)
typedef __attribute__((ext_vector_type(4))) float float4e;  // 4 x fp32 acc
typedef __attribute__((ext_vector_type(16))) float f32x16;  // 32x32 acc

#define LOG2E 1.4426950408889634f

__device__ __forceinline__ ushort f2bf(float f) {
    union { float f; unsigned u; } v; v.f = f;
    unsigned r = v.u + 0x7FFF + ((v.u >> 16) & 1);
    return (ushort)(r >> 16);
}

// packed RNE fp32x2 -> bf16x2 (v_cvt_pk_bf16_f32); low 16 bits = first arg
__device__ __forceinline__ unsigned pk2bf(float a, float b) {
    float2 t; t.x = a; t.y = b;
    __hip_bfloat162 h = __float22bfloat162_rn(t);
    union { __hip_bfloat162 h; unsigned u; } cv; cv.h = h;
    return cv.u;
}

// raw v_exp_f32 (2^x), no libm wrapper
__device__ __forceinline__ float fexp2(float x) {
    return __builtin_amdgcn_exp2f(x);
}

// async 16B global -> LDS; LDS dest = wave-uniform base + lane*16.
__device__ __forceinline__ void async_cp16(const ushort* g, ushort* l) {
    __builtin_amdgcn_global_load_lds(
        (const __attribute__((address_space(1))) unsigned int*)g,
        (__attribute__((address_space(3))) unsigned int*)l,
        16, 0, 0);
}

// ===========================================================================
// Fused prep: blocks 0..575 = weight transposes (z = bid/144; Wq scaled by
// log2e for the exp2-domain attn); blocks 576..3647 = x fp32->bf16 cast.
// ===========================================================================
__global__ __launch_bounds__(256) void prep_fused(
    const float* __restrict__ xin, ushort* __restrict__ xout,
    const float* __restrict__ W0, const float* __restrict__ W1,
    const float* __restrict__ W2, const float* __restrict__ W3,
    ushort* __restrict__ WtBase)
{
    const int bid = blockIdx.x;
    const int tid = threadIdx.x;

    if (bid < 576) {
        __shared__ float t[64][65];
        const int z   = bid / 144;
        const int rem = bid - z * 144;
        const int by  = rem / 12, bx = rem - by * 12;
        const float* W = (z == 0) ? W0 : (z == 1) ? W1 : (z == 2) ? W2 : W3;
        const float scale = (z == 0) ? LOG2E : 1.0f;   // fold log2e into Wq
        ushort* Wt = WtBase + (size_t)z * (768u * 768u);

        const int c  = tid & 63;
        const int rg = tid >> 6;
        const int k0 = by * 64, n0 = bx * 64;
        #pragma unroll
        for (int r = 0; r < 16; ++r) {
            const int row = rg * 16 + r;
            t[row][c] = W[(size_t)(k0 + row) * 768 + n0 + c];
        }
        __syncthreads();
        #pragma unroll
        for (int r = 0; r < 16; ++r) {
            const int row = rg * 16 + r;
            Wt[(size_t)(n0 + row) * 768 + k0 + c] = f2bf(t[c][row] * scale);
        }
    } else {
        const int i = (bid - 576) * 256 + tid;      // < 786432 = XE/4
        float4 v = *(const float4*)&xin[(size_t)i * 4];
        ushort4 o;
        o.x = f2bf(v.x); o.y = f2bf(v.y); o.z = f2bf(v.z); o.w = f2bf(v.w);
        *(ushort4*)&xout[(size_t)i * 4] = o;
    }
}

// ===========================================================================
// Fused QKV GEMM: Out[M,2304] = x[M,768] @ [Wq|Wk|Wv]^T + [bq|bk|bv]
// 128x128 tile, BK=32, 4 waves 2x2, 16 accs/wave. 2-phase async pipeline.
// seg 0 bias (bq) scaled by log2e. seg 2 (V): in-LDS transpose epilogue
// writes VT[b][h][d][s] directly (transpose_v kernel eliminated).
// ===========================================================================
__global__ __launch_bounds__(256) void gemm_qkv_fused(
    const ushort* __restrict__ A, const ushort* __restrict__ Bt,
    const float* __restrict__ bq, const float* __restrict__ bk,
    const float* __restrict__ bv, ushort* __restrict__ Outbase,
    ushort* __restrict__ VTout)
{
    constexpr int K = 768;
    __shared__ union {
        struct {                        // K-loop stage buffers
            ushort As[2][128][32];      // unpadded: required by global_load_lds
            ushort Bs[2][128][32];
        } g;
        ushort T[128][128];             // seg==2 epilogue transpose tile
    } S;

    const int tid  = threadIdx.x;
    const int w    = tid >> 6;
    const int lane = tid & 63;
    const int l16  = lane & 15;
    const int quad = lane >> 4;
    const int wr   = (w >> 1) * 64;
    const int wc   = (w & 1) * 64;
    const int row0 = blockIdx.y * 128, col0 = blockIdx.x * 128;

    const int r4 = lane >> 2;
    const int c8 = (lane & 3) * 8;

    float4e acc[4][4];
    #pragma unroll
    for (int mi = 0; mi < 4; ++mi)
        #pragma unroll
        for (int ni = 0; ni < 4; ++ni) acc[mi][ni] = (float4e){0.f,0.f,0.f,0.f};

    // prologue: stage K-step 0 into buf 0
    #pragma unroll
    for (int i = 0; i < 2; ++i) {
        const int rr = w * 32 + i * 16;
        async_cp16(&A [(size_t)(row0 + rr + r4) * K + c8], &S.g.As[0][rr][0]);
        async_cp16(&Bt[(size_t)(col0 + rr + r4) * K + c8], &S.g.Bs[0][rr][0]);
    }
    __syncthreads();   // implicit vmcnt(0) drain

    for (int k0 = 0; k0 < K; k0 += 32) {
        const int cur = (k0 >> 5) & 1;
        if (k0 + 32 < K) {            // issue next-step DMA before compute
            #pragma unroll
            for (int i = 0; i < 2; ++i) {
                const int rr = w * 32 + i * 16;
                async_cp16(&A [(size_t)(row0 + rr + r4) * K + k0 + 32 + c8],
                           &S.g.As[cur ^ 1][rr][0]);
                async_cp16(&Bt[(size_t)(col0 + rr + r4) * K + k0 + 32 + c8],
                           &S.g.Bs[cur ^ 1][rr][0]);
            }
        }

        short8 af[4], bf[4];
        #pragma unroll
        for (int i = 0; i < 4; ++i) {
            af[i] = *(const short8*)&S.g.As[cur][wr + i * 16 + l16][quad * 8];
            bf[i] = *(const short8*)&S.g.Bs[cur][wc + i * 16 + l16][quad * 8];
        }
        #pragma unroll
        for (int mi = 0; mi < 4; ++mi)
            #pragma unroll
            for (int ni = 0; ni < 4; ++ni)
                acc[mi][ni] = __builtin_amdgcn_mfma_f32_16x16x32_bf16(
                    af[mi], bf[ni], acc[mi][ni], 0, 0, 0);
        __syncthreads();  // next-step staged + this step's reads drained
    }

    const int seg = (col0 >= 1536) ? 2 : (col0 >= 768 ? 1 : 0);
    const float* bias = (seg == 0) ? bq : (seg == 1) ? bk : bv;
    const float bscale = (seg == 0) ? LOG2E : 1.0f;
    const int ncol0 = col0 - seg * 768 + wc;

    if (seg < 2) {
        ushort* outp = Outbase + (size_t)seg * (4096u * 768u);
        #pragma unroll
        for (int ni = 0; ni < 4; ++ni) {
            const int col = ncol0 + ni * 16 + l16;
            const float bs = bias[col] * bscale;
            #pragma unroll
            for (int mi = 0; mi < 4; ++mi) {
                #pragma unroll
                for (int r = 0; r < 4; ++r) {
                    const int row = row0 + wr + mi * 16 + quad * 4 + r;
                    outp[(size_t)row * 768 + col] = f2bf(acc[mi][ni][r] + bs);
                }
            }
        }
    } else {
        // ---- V: in-LDS transpose (stage buffers dead after loop-final
        // barrier), then coalesced VT[b][h][d][s] write.
        // T[cl][rl] stored with 8B-granule swizzle g' = g ^ (cl&15).
        #pragma unroll
        for (int ni = 0; ni < 4; ++ni) {
            const int cl   = wc + ni * 16 + l16;          // tile-local col
            const float bs = bias[ncol0 + ni * 16 + l16]; // = bias[col0-1536+cl]
            #pragma unroll
            for (int mi = 0; mi < 4; ++mi) {
                const int rl0 = wr + mi * 16 + quad * 4;  // 4-aligned row
                const int gp  = (rl0 >> 2) ^ (cl & 15);
                uint2 pk;
                pk.x = (unsigned)f2bf(acc[mi][ni][0] + bs)
                     | ((unsigned)f2bf(acc[mi][ni][1] + bs) << 16);
                pk.y = (unsigned)f2bf(acc[mi][ni][2] + bs)
                     | ((unsigned)f2bf(acc[mi][ni][3] + bs) << 16);
                *(uint2*)&S.T[cl][gp * 4] = pk;
            }
        }
        __syncthreads();
        const int cl = tid >> 1;                  // 0..127: tile-local col
        const int hf = tid & 1;                   // row half (0: 0..63)
        const int vcol = (col0 - 1536) + cl;      // 0..767
        const int hh = vcol >> 6, dd = vcol & 63;
        const int bb = row0 >> 11;                // 128 | 2048 -> uniform
        const int ss = (row0 & 2047) + hf * 64;
        ushort tmp[64];
        #pragma unroll
        for (int c2 = 0; c2 < 16; ++c2) {
            const int gp = (hf * 16 + c2) ^ (cl & 15);
            *(uint2*)&tmp[c2 * 4] = *(const uint2*)&S.T[cl][gp * 4];
        }
        ushort* dst = &VTout[((size_t)(bb * 12 + hh) * 64 + dd) * 2048 + ss];
        #pragma unroll
        for (int j = 0; j < 8; ++j)
            *(uint4*)&dst[j * 8] = *(const uint4*)&tmp[j * 8];
    }
}

// ===========================================================================
// Wo GEMM: C[4096,768](fp32) = ctx[4096,768] @ Wo^T + bo. 128x128 tile,
// 2-phase async DMA pipeline.
// ===========================================================================
__global__ __launch_bounds__(256) void gemm_wo_128(
    const ushort* __restrict__ A, const ushort* __restrict__ Bt,
    const float* __restrict__ bias, float* __restrict__ Cout)
{
    constexpr int K = 768, N = 768;
    __shared__ ushort As[2][128][32];
    __shared__ ushort Bs[2][128][32];

    const int tid  = threadIdx.x;
    const int w    = tid >> 6;
    const int lane = tid & 63;
    const int l16  = lane & 15;
    const int quad = lane >> 4;
    const int wr   = (w >> 1) * 64;
    const int wc   = (w & 1) * 64;
    const int row0 = blockIdx.y * 128, col0 = blockIdx.x * 128;

    const int r4 = lane >> 2;
    const int c8 = (lane & 3) * 8;

    float4e acc[4][4];
    #pragma unroll
    for (int mi = 0; mi < 4; ++mi)
        #pragma unroll
        for (int ni = 0; ni < 4; ++ni) acc[mi][ni] = (float4e){0.f,0.f,0.f,0.f};

    // prologue: stage K-step 0 into buf 0
    #pragma unroll
    for (int i = 0; i < 2; ++i) {
        const int rr = w * 32 + i * 16;
        async_cp16(&A [(size_t)(row0 + rr + r4) * K + c8], &As[0][rr][0]);
        async_cp16(&Bt[(size_t)(col0 + rr + r4) * K + c8], &Bs[0][rr][0]);
    }
    __syncthreads();

    for (int k0 = 0; k0 < K; k0 += 32) {
        const int cur = (k0 >> 5) & 1;
        if (k0 + 32 < K) {
            #pragma unroll
            for (int i = 0; i < 2; ++i) {
                const int rr = w * 32 + i * 16;
                async_cp16(&A [(size_t)(row0 + rr + r4) * K + k0 + 32 + c8],
                           &As[cur ^ 1][rr][0]);
                async_cp16(&Bt[(size_t)(col0 + rr + r4) * K + k0 + 32 + c8],
                           &Bs[cur ^ 1][rr][0]);
            }
        }

        short8 af[4], bf[4];
        #pragma unroll
        for (int i = 0; i < 4; ++i) {
            af[i] = *(const short8*)&As[cur][wr + i * 16 + l16][quad * 8];
            bf[i] = *(const short8*)&Bs[cur][wc + i * 16 + l16][quad * 8];
        }
        #pragma unroll
        for (int mi = 0; mi < 4; ++mi)
            #pragma unroll
            for (int ni = 0; ni < 4; ++ni)
                acc[mi][ni] = __builtin_amdgcn_mfma_f32_16x16x32_bf16(
                    af[mi], bf[ni], acc[mi][ni], 0, 0, 0);
        __syncthreads();
    }

    #pragma unroll
    for (int ni = 0; ni < 4; ++ni) {
        const int col = col0 + wc + ni * 16 + l16;
        const float bs = bias[col];
        #pragma unroll
        for (int mi = 0; mi < 4; ++mi) {
            #pragma unroll
            for (int r = 0; r < 4; ++r) {
                const int row = row0 + wr + mi * 16 + quad * 4 + r;
                Cout[(size_t)row * N + col] = acc[mi][ni][r] + bs;
            }
        }
    }
}

// ===========================================================================
// Flash attention, 32x32 MFMA, zero-shuffle softmax+PV. 512 thr = 8 waves.
// R23 verbatim (proven 55.4us): log2-domain scores -> raw v_exp_f32;
// THR = 8*log2e; K and V both double-buffered; 1 barrier/tile.
// Wave w: qg = w&1 (32 q), ks = w>>1 (32-key slice of 128-key tile).
// C-layout (HW-verified): col=l&31, row=(r&3)+8*(r>>2)+4*(l>>5).
// sigma_m(hi*8+j') = 4hi+(j'&3)+8*(j'>>2)+16m on BOTH PV operands.
// Swizzles (both-sides, rule 21): K granule ^(row&7); V granule ^(d&7).
// Pipeline: stage t+1 (4 DMA) -> compute t -> 1 barrier. 16 tiles.
// ===========================================================================
__global__ __launch_bounds__(512, 4) void attn_mfma(
    const ushort* __restrict__ Qg, const ushort* __restrict__ Kgl,
    const ushort* __restrict__ VT, ushort* __restrict__ Ctx)
{
    constexpr int S = 2048, D = 768;
    __shared__ union {
        struct {                      // main-loop stage buffers (swizzled)
            ushort Ks [2][128][64];   // [buf][key][16B-gran ^ (key&7)]
            ushort Vts[2][64][128];   // [buf][d][16B-gran ^ (d&7)]
        } s;
        struct {                      // epilogue split-K combine buffers
            float Osc[6][2048];       // [slot][lane*32 + (g^(lane&7))*4 + e]
            float Msc[6][32];
            float Lsc[6][32];
        } c;
    } U;

    const int tid  = threadIdx.x;
    const int w    = tid >> 6;        // 0..7
    const int qg   = w & 1;           // query group (32 q)
    const int ks   = w >> 1;          // key slice 0..3 (32 of 128)
    const int lane = tid & 63;
    const int l31  = lane & 31;
    const int hi   = lane >> 5;
    const int b = blockIdx.z, h = blockIdx.y, q0 = blockIdx.x * 64;
    const size_t hc = (size_t)h * 64;

    // Q fragments (B-operand): yq[dc][j'] = Q[q][dc*16 + hi*8 + j']
    const size_t qrow = (size_t)(b * S + q0 + qg * 32 + l31) * D + hc + hi * 8;
    short8 yq[4];
    #pragma unroll
    for (int dc = 0; dc < 4; ++dc) yq[dc] = *(const short8*)&Qg[qrow + dc * 16];

    // ---- staging (rule 21: pre-swizzled global source, linear LDS dest) ----
    const int sr  = tid >> 3;                    // K row 0..63 (+64 2nd issue)
    const int kgr = (tid & 7) ^ (sr & 7);        // 16B granule of 8
    const ushort* srcK = &Kgl[(size_t)(b * S + sr) * D + hc + kgr * 8];
    const int vr  = tid >> 4;                    // V row 0..31 (+32 2nd issue)
    const int vgr = (tid & 15) ^ (vr & 7);       // 16B granule of 16
    const ushort* srcV = &VT[((size_t)(b * 12 + h) * 64 + vr) * 2048 + vgr * 8];
    ushort* dK0 = &U.s.Ks [0][w * 8][0];         // wave-uniform bases
    ushort* dK1 = &U.s.Ks [1][w * 8][0];
    ushort* dV0 = &U.s.Vts[0][w * 4][0];
    ushort* dV1 = &U.s.Vts[1][w * 4][0];

    // ---- loop-invariant swizzled read offsets (ushort units) ----
    int okf[4];                                  // K b128: row ks*32+l31
    #pragma unroll
    for (int dc = 0; dc < 4; ++dc)
        okf[dc] = (ks * 32 + l31) * 64 + ((dc * 2 + hi) ^ (l31 & 7)) * 8;
    int ovo[2][2][2];                            // V b64: [a][m][chunk]
    #pragma unroll
    for (int a = 0; a < 2; ++a)
        #pragma unroll
        for (int m = 0; m < 2; ++m)
            #pragma unroll
            for (int c2 = 0; c2 < 2; ++c2)
                ovo[a][m][c2] = (a * 32 + l31) * 128 +
                    ((ks * 4 + m * 2 + c2) ^ (l31 & 7)) * 8 + hi * 4;

    float m_ = -1e30f, l_ = 0.f;
    f32x16 oa0, oa1;
    #pragma unroll
    for (int i = 0; i < 16; ++i) { oa0[i] = 0.f; oa1[i] = 0.f; }

    // prologue: stage tile 0 into buf 0
    async_cp16(srcK,                  dK0);
    async_cp16(srcK + (size_t)64 * D, dK0 + 64 * 64);
    async_cp16(srcV,                  dV0);
    async_cp16(srcV + 32 * 2048,      dV0 + 32 * 128);
    __syncthreads();                  // implicit vmcnt(0) drain

    #pragma unroll 2
    for (int t = 0; t < 16; ++t) {
        const int cur = t & 1;
        const ushort* ksb = cur ? &U.s.Ks [1][0][0] : &U.s.Ks [0][0][0];
        const ushort* vsb = cur ? &U.s.Vts[1][0][0] : &U.s.Vts[0][0][0];
        if (t + 1 < 16) {             // issue next-tile DMA before compute
            const size_t kn = (size_t)(t + 1) * 128;
            ushort* dK = cur ? dK0 : dK1;
            ushort* dV = cur ? dV0 : dV1;
            async_cp16(srcK + kn * D,              dK);
            async_cp16(srcK + (kn + 64) * D,       dK + 64 * 64);
            async_cp16(srcV + kn,                  dV);
            async_cp16(srcV + kn + 32 * 2048,      dV + 32 * 128);
        }

        // ---- scores: S^T[32k x 32q] in log2 domain, 4 chained MFMAs ----
        f32x16 sa;
        #pragma unroll
        for (int i = 0; i < 16; ++i) sa[i] = 0.f;
        __builtin_amdgcn_s_setprio(1);
        #pragma unroll
        for (int dc = 0; dc < 4; ++dc) {
            const short8 xk = *(const short8*)&ksb[okf[dc]];
            sa = __builtin_amdgcn_mfma_f32_32x32x16_bf16(xk, yq[dc], sa, 0, 0, 0);
        }
        __builtin_amdgcn_s_setprio(0);

        // ---- online softmax (log2 domain): 15 fmax + 1 shfl32 ----
        float mx = sa[0];
        #pragma unroll
        for (int r = 1; r < 16; ++r) mx = fmaxf(mx, sa[r]);
        mx = fmaxf(mx, __shfl_xor(mx, 32, 64));

        // defer-max (T13): THR = 8*log2e -> P bounded by e^8, as before.
        const bool full = !__all(mx - m_ <= 11.5415603f);
        if (full) {
            const float mn = fmaxf(m_, mx);
            const float alpha = fexp2(m_ - mn);    // first iter: 0
            l_ *= alpha;
            m_ = mn;
            #pragma unroll
            for (int i = 0; i < 16; ++i) { oa0[i] *= alpha; oa1[i] *= alpha; }
        }

        float p[16], ps = 0.f;
        #pragma unroll
        for (int r = 0; r < 16; ++r) {
            p[r] = fexp2(sa[r] - m_);              // bare v_exp_f32
            ps += p[r];
        }
        ps += __shfl_xor(ps, 32, 64);
        l_ += ps;

        // ---- PV B-operands: own p[] packed (slot j' = p[8m + j']) ----
        union { unsigned u[4]; short8 s8; } pa0, pa1;
        pa0.u[0] = pk2bf(p[0],  p[1]);  pa0.u[1] = pk2bf(p[2],  p[3]);
        pa0.u[2] = pk2bf(p[4],  p[5]);  pa0.u[3] = pk2bf(p[6],  p[7]);
        pa1.u[0] = pk2bf(p[8],  p[9]);  pa1.u[1] = pk2bf(p[10], p[11]);
        pa1.u[2] = pk2bf(p[12], p[13]); pa1.u[3] = pk2bf(p[14], p[15]);

        // ---- PV: O^T[64d x 32q] += V^T x P (4 MFMAs, 8 b64 V-reads) ----
        __builtin_amdgcn_s_setprio(1);
        {
            union { uint2 v2[2]; short8 s8; } xv;
            xv.v2[0] = *(const uint2*)&vsb[ovo[0][0][0]];
            xv.v2[1] = *(const uint2*)&vsb[ovo[0][0][1]];
            oa0 = __builtin_amdgcn_mfma_f32_32x32x16_bf16(xv.s8, pa0.s8, oa0, 0, 0, 0);
            xv.v2[0] = *(const uint2*)&vsb[ovo[0][1][0]];
            xv.v2[1] = *(const uint2*)&vsb[ovo[0][1][1]];
            oa0 = __builtin_amdgcn_mfma_f32_32x32x16_bf16(xv.s8, pa1.s8, oa0, 0, 0, 0);
            xv.v2[0] = *(const uint2*)&vsb[ovo[1][0][0]];
            xv.v2[1] = *(const uint2*)&vsb[ovo[1][0][1]];
            oa1 = __builtin_amdgcn_mfma_f32_32x32x16_bf16(xv.s8, pa0.s8, oa1, 0, 0, 0);
            xv.v2[0] = *(const uint2*)&vsb[ovo[1][1][0]];
            xv.v2[1] = *(const uint2*)&vsb[ovo[1][1][1]];
            oa1 = __builtin_amdgcn_mfma_f32_32x32x16_bf16(xv.s8, pa1.s8, oa1, 0, 0, 0);
        }
        __builtin_amdgcn_s_setprio(0);

        __syncthreads();  // implicit vmcnt(0): tile t+1 staged; buf reads done
    }

    // ---- 4-way split-K combine (stage buffers dead; union reuse) ----
    if (ks > 0) {
        const int slot = (ks - 1) * 2 + qg;
        float* ob = &U.c.Osc[slot][lane * 32];
        #pragma unroll
        for (int g = 0; g < 4; ++g) {
            float4 v0, v1;
            v0.x = oa0[g * 4 + 0]; v0.y = oa0[g * 4 + 1];
            v0.z = oa0[g * 4 + 2]; v0.w = oa0[g * 4 + 3];
            v1.x = oa1[g * 4 + 0]; v1.y = oa1[g * 4 + 1];
            v1.z = oa1[g * 4 + 2]; v1.w = oa1[g * 4 + 3];
            *(float4*)&ob[(( g     ) ^ (lane & 7)) * 4] = v0;
            *(float4*)&ob[(((g + 4)) ^ (lane & 7)) * 4] = v1;
        }
        if (hi == 0) {
            U.c.Msc[slot][l31] = m_;
            U.c.Lsc[slot][l31] = l_;
        }
    }
    __syncthreads();
    if (ks == 0) {
        const float m1 = U.c.Msc[qg][l31];
        const float m2 = U.c.Msc[2 + qg][l31];
        const float m3 = U.c.Msc[4 + qg][l31];
        const float M  = fmaxf(fmaxf(m_, m1), fmaxf(m2, m3));
        const float a0 = fexp2(m_ - M), a1 = fexp2(m1 - M),
                    a2 = fexp2(m2 - M), a3 = fexp2(m3 - M);
        const float l1 = U.c.Lsc[qg][l31];
        const float l2 = U.c.Lsc[2 + qg][l31];
        const float l3 = U.c.Lsc[4 + qg][l31];
        const float inv = 1.0f / (l_ * a0 + l1 * a1 + l2 * a2 + l3 * a3);

        float o[32];
        #pragma unroll
        for (int i = 0; i < 16; ++i) { o[i] = oa0[i] * a0; o[16 + i] = oa1[i] * a0; }
        #pragma unroll
        for (int s = 0; s < 3; ++s) {
            const float as = (s == 0) ? a1 : (s == 1) ? a2 : a3;
            const float* ob = &U.c.Osc[s * 2 + qg][lane * 32];
            #pragma unroll
            for (int gg = 0; gg < 8; ++gg) {
                const float4 v = *(const float4*)&ob[(gg ^ (lane & 7)) * 4];
                o[gg * 4 + 0] += v.x * as;
                o[gg * 4 + 1] += v.y * as;
                o[gg * 4 + 2] += v.z * as;
                o[gg * 4 + 3] += v.w * as;
            }
        }

        // lane owns q = q0+qg*32+l31; d = a*32 + 8*rq + 4*hi + e
        const size_t crow = (size_t)(b * S + q0 + qg * 32 + l31) * D + hc;
        #pragma unroll
        for (int a = 0; a < 2; ++a)
            #pragma unroll
            for (int rq = 0; rq < 4; ++rq) {
                const int base = a * 16 + rq * 4;
                uint2 ov;
                ov.x = pk2bf(o[base + 0] * inv, o[base + 1] * inv);
                ov.y = pk2bf(o[base + 2] * inv, o[base + 3] * inv);
                *(uint2*)&Ctx[crow + a * 32 + rq * 8 + hi * 4] = ov;
            }
    }
}

// ===========================================================================
// Launch
// ===========================================================================
extern "C" void kernel_launch(void* const* d_in, const int* in_sizes, int n_in,
                              void* d_out, int out_size, void* d_ws, size_t ws_size,
                              hipStream_t stream)
{
    const float* x  = (const float*)d_in[0];
    const float* Wq = (const float*)d_in[1];
    const float* bq = (const float*)d_in[2];
    const float* Wk = (const float*)d_in[3];
    const float* bk = (const float*)d_in[4];
    const float* Wv = (const float*)d_in[5];
    const float* bv = (const float*)d_in[6];
    const float* Wo = (const float*)d_in[7];
    const float* bo = (const float*)d_in[8];

    const int M = 4096, D = 768;
    const size_t XE = (size_t)M * D;     // 3,145,728
    const size_t WE = (size_t)D * D;     //   589,824

    ushort* xb   = (ushort*)d_ws;
    ushort* wtq  = xb   + XE;            // wtq/wtk/wtv/wto contiguous
    ushort* wto  = wtq  + 3 * WE;
    ushort* qb   = wto  + WE;            // qb/kb contiguous
    ushort* kb   = qb   + XE;
    ushort* vt   = kb   + XE;            // V^T written directly by qkv GEMM
    ushort* ctxb = vt   + XE;

    // fused prep: 576 weight-transpose blocks + 3072 cast blocks
    prep_fused<<<dim3(576 + 3072), 256, 0, stream>>>(
        x, xb, Wq, Wk, Wv, Wo, wtq);

    gemm_qkv_fused<<<dim3(2304 / 128, 4096 / 128), 256, 0, stream>>>(
        xb, wtq, bq, bk, bv, qb, vt);

    attn_mfma<<<dim3(2048 / 64, 12, 2), 512, 0, stream>>>(qb, kb, vt, ctxb);

    gemm_wo_128<<<dim3(768 / 128, 4096 / 128), 256, 0, stream>>>(
        ctxb, wto, bo, (float*)d_out);
}